// Round 12
// baseline (177.445 us; speedup 1.0000x reference)
//
#include <hip/hip_runtime.h>

typedef __attribute__((ext_vector_type(8))) short bf16x8;
typedef __attribute__((ext_vector_type(4))) float f32x4;
typedef __attribute__((ext_vector_type(16))) float f32x16;
typedef __attribute__((ext_vector_type(4))) float float4v;
typedef __attribute__((ext_vector_type(4))) unsigned short ushort4v;
typedef __attribute__((ext_vector_type(8))) unsigned short ushort8v;

#define DEVINL __device__ __forceinline__

// B=8, C=768, T=1024, heads=12, ch=64, EC=768, S_enc=256, S_tot=1280, groups=32

DEVINL unsigned short f2bf(float f) {
  union { float f; unsigned u; } v; v.f = f;
  unsigned r = (v.u + 0x7fffu + ((v.u >> 16) & 1u)) >> 16;  // RNE
  return (unsigned short)r;
}
DEVINL float bf2f(unsigned short h) {
  union { unsigned u; float f; } v; v.u = ((unsigned)h) << 16;
  return v.f;
}
DEVINL float exp2a(float x) {
  float r; asm("v_exp_f32 %0, %1" : "=v"(r) : "v"(x)); return r;
}
DEVINL unsigned cvtpk(float lo, float hi) {  // dst = bf16(lo) | bf16(hi)<<16, RNE
  unsigned r;
  asm("v_cvt_pk_bf16_f32 %0, %1, %2" : "=v"(r) : "v"(lo), "v"(hi));
  return r;
}
DEVINL void gload16(const void* g, void* l) {
  __builtin_amdgcn_global_load_lds(
      (const __attribute__((address_space(1))) unsigned*)g,
      (__attribute__((address_space(3))) unsigned*)l, 16, 0, 0);
}
DEVINL void plswap(unsigned& a, unsigned& b) {  // a'={a.lo,b.lo}, b'={a.hi,b.hi}
  asm("v_permlane32_swap_b32 %0, %1" : "+v"(a), "+v"(b));
}
DEVINL bf16x8 mkfrag(unsigned a, unsigned b, unsigned c, unsigned d) {
  union { unsigned u[4]; bf16x8 v; } x;
  x.u[0] = a; x.u[1] = b; x.u[2] = c; x.u[3] = d;
  return x.v;
}
#define WAITV0 asm volatile("s_waitcnt vmcnt(0)" ::: "memory")
#define WAITV4 asm volatile("s_waitcnt vmcnt(4)" ::: "memory")
#define RBAR  __builtin_amdgcn_s_barrier()

// ---------------- fused fp32 -> bf16 weight convert (all 3 weights) ----------------
__global__ __launch_bounds__(256) void k_cvt3(const float* __restrict__ s0,
                                              const float* __restrict__ s1,
                                              const float* __restrict__ s2,
                                              unsigned short* __restrict__ d) {
  int i = blockIdx.x * 256 + threadIdx.x;  // 884736 float4s total
  const float* s; int off;
  if (i < 442368)      { s = s0; off = i; }
  else if (i < 737280) { s = s1; off = i - 442368; }
  else                 { s = s2; off = i - 737280; }
  float4v v = *(const float4v*)(s + (size_t)off * 4);
  ushort4v o;
  o[0] = f2bf(v[0]); o[1] = f2bf(v[1]); o[2] = f2bf(v[2]); o[3] = f2bf(v[3]);
  *(ushort4v*)(d + (size_t)i * 4) = o;
}

// ---------------- GroupNorm + transpose -> xn_t[b][t][c] bf16 ----------------
__global__ __launch_bounds__(256) void k_gn(const float* __restrict__ x,
                                            const float* __restrict__ gw,
                                            const float* __restrict__ gb,
                                            unsigned short* __restrict__ xnt) {
  int g = blockIdx.x, b = blockIdx.y, tid = threadIdx.x;
  const float* xb = x + ((size_t)b * 768 + g * 24) * 1024;
  float s = 0.f, ss = 0.f;
  for (int i = tid; i < 6144; i += 256) {
    float4v v = *(const float4v*)(xb + (size_t)i * 4);
    s += v[0] + v[1] + v[2] + v[3];
    ss += v[0] * v[0] + v[1] * v[1] + v[2] * v[2] + v[3] * v[3];
  }
  #pragma unroll
  for (int o = 32; o > 0; o >>= 1) { s += __shfl_down(s, o); ss += __shfl_down(ss, o); }
  __shared__ float rs[4], rss[4], stat[2];
  int w = tid >> 6;
  if ((tid & 63) == 0) { rs[w] = s; rss[w] = ss; }
  __syncthreads();
  if (tid == 0) {
    float S = rs[0] + rs[1] + rs[2] + rs[3], SS = rss[0] + rss[1] + rss[2] + rss[3];
    float mean = S / 24576.f;
    float var = SS / 24576.f - mean * mean;
    stat[0] = mean; stat[1] = rsqrtf(fmaxf(var, 0.f) + 1e-5f);
  }
  __syncthreads();
  float mean = stat[0], rstd = stat[1];
  float wv[24], bv[24];
  #pragma unroll
  for (int c = 0; c < 24; ++c) { wv[c] = gw[g * 24 + c]; bv[c] = gb[g * 24 + c]; }
  for (int it = 0; it < 4; ++it) {
    int t = it * 256 + tid;
    ushort8v ov[3];
    #pragma unroll
    for (int c = 0; c < 24; ++c) {
      float v = xb[(size_t)c * 1024 + t];
      ov[c >> 3][c & 7] = f2bf((v - mean) * rstd * wv[c] + bv[c]);
    }
    ushort8v* dst = (ushort8v*)(xnt + ((size_t)(b * 1024 + t)) * 768 + g * 24);
    dst[0] = ov[0]; dst[1] = ov[1]; dst[2] = ov[2];
  }
}

// ---------------- encoder transpose -> enc_t[b][s][c] bf16 ----------------
__global__ __launch_bounds__(256) void k_enc_tr(const float* __restrict__ enc,
                                                unsigned short* __restrict__ et) {
  int ct = blockIdx.x * 64, st = blockIdx.y * 64, b = blockIdx.z, tid = threadIdx.x;
  __shared__ unsigned short L[64 * 72];
  #pragma unroll
  for (int it = 0; it < 4; ++it) {
    int idx = it * 256 + tid; int r = idx >> 4, ch = idx & 15;
    float4v v = *(const float4v*)(enc + ((size_t)(b * 768 + ct + r)) * 256 + st + ch * 4);
    ushort4v o;
    o[0] = f2bf(v[0]); o[1] = f2bf(v[1]); o[2] = f2bf(v[2]); o[3] = f2bf(v[3]);
    *(ushort4v*)&L[r * 72 + ch * 4] = o;
  }
  __syncthreads();
  #pragma unroll
  for (int it = 0; it < 2; ++it) {
    int idx = it * 256 + tid; int s = idx >> 3, ch = idx & 7;
    ushort8v o;
    #pragma unroll
    for (int j = 0; j < 8; ++j) o[j] = L[(ch * 8 + j) * 72 + s];
    *(ushort8v*)(et + ((size_t)(b * 256 + st + s)) * 768 + ct + ch * 8) = o;
  }
}

// ---------------- build vcat[bh][c][s] bf16 ----------------
__global__ __launch_bounds__(256) void k_vcat(const unsigned short* __restrict__ qkvt,
                                              const unsigned short* __restrict__ ekvt,
                                              unsigned short* __restrict__ vcat) {
  int s0 = blockIdx.x * 64, bh = blockIdx.y, b = bh / 12, h = bh % 12, tid = threadIdx.x;
  __shared__ unsigned short L[64 * 72];
  #pragma unroll
  for (int it = 0; it < 2; ++it) {
    int idx = it * 256 + tid; int s = idx >> 3, ch = idx & 7;
    int sg = s0 + s;
    const unsigned short* src = (sg < 256)
        ? ekvt + ((size_t)(b * 256 + sg)) * 1536 + h * 128 + 64 + ch * 8
        : qkvt + ((size_t)(b * 1024 + sg - 256)) * 2304 + h * 192 + 128 + ch * 8;
    *(ushort8v*)&L[s * 72 + ch * 8] = *(const ushort8v*)src;
  }
  __syncthreads();
  #pragma unroll
  for (int it = 0; it < 2; ++it) {
    int idx = it * 256 + tid; int c = idx >> 3, ch = idx & 7;
    ushort8v o;
    #pragma unroll
    for (int j = 0; j < 8; ++j) o[j] = L[(ch * 8 + j) * 72 + c];
    *(ushort8v*)(vcat + ((size_t)bh * 64 + c) * 1280 + s0 + ch * 8) = o;
  }
}

// ------ GEMM: C[M][N] = A[M][K]*B[N][K]^T. BM x 128 tile, BK=32, 2-buf (R11) ------
template <int EPI, int BM>
__global__ __launch_bounds__(256, 4) void k_gemm(const unsigned short* __restrict__ A,
                                                 const unsigned short* __restrict__ B,
                                                 const float* __restrict__ bias,
                                                 const float* __restrict__ resid,
                                                 void* __restrict__ outp,
                                                 int N, int K,
                                                 long sA, long sB, long sO, long sR) {
  constexpr int MI = BM / 32;
  int bz = blockIdx.z;
  int m0 = blockIdx.x * BM, n0 = blockIdx.y * 128;
  const unsigned short* Ab = A + (size_t)bz * sA + (size_t)m0 * K;
  const unsigned short* Bb = B + (size_t)bz * sB + (size_t)n0 * K;
  __shared__ unsigned short As[2][BM * 32], Bs[2][128 * 32];
  int tid = threadIdx.x, lane = tid & 63, w = tid >> 6;
  int ln = lane & 15, lg = lane >> 4;
  int wm = (w >> 1) * (BM / 2), wn = (w & 1) * 64;
  int sr = tid >> 2, sc = tid & 3;
  const unsigned short* gA = Ab + (size_t)sr * K + ((sc ^ (sr & 3)) * 8);
  const unsigned short* gB = Bb + (size_t)sr * K + ((sc ^ (sr & 3)) * 8);
  int swz = (lg ^ (ln & 3)) * 8;

  f32x4 acc[MI][4];
  #pragma unroll
  for (int i = 0; i < MI; ++i)
    #pragma unroll
    for (int j = 0; j < 4; ++j) acc[i][j] = (f32x4){0.f, 0.f, 0.f, 0.f};

  auto stageAB = [&](int buf, int k0) {
    unsigned short* ad = &As[buf][0] + w * 512;
    unsigned short* bd = &Bs[buf][0] + w * 512;
    gload16(gA + k0, ad);
    if constexpr (BM == 128) gload16(gA + (size_t)64 * K + k0, ad + 2048);
    gload16(gB + k0, bd);
    gload16(gB + (size_t)64 * K + k0, bd + 2048);
  };
  auto WAITP = [&] {
    if constexpr (BM == 128) asm volatile("s_waitcnt vmcnt(4)" ::: "memory");
    else                     asm volatile("s_waitcnt vmcnt(3)" ::: "memory");
  };
  auto comp = [&](int buf) {
    bf16x8 af[MI], bfv[4];
    #pragma unroll
    for (int i = 0; i < MI; ++i) af[i] = *(const bf16x8*)&As[buf][(wm + i * 16 + ln) * 32 + swz];
    #pragma unroll
    for (int j = 0; j < 4; ++j) bfv[j] = *(const bf16x8*)&Bs[buf][(wn + j * 16 + ln) * 32 + swz];
    #pragma unroll
    for (int i = 0; i < MI; ++i)
      #pragma unroll
      for (int j = 0; j < 4; ++j)
        acc[i][j] = __builtin_amdgcn_mfma_f32_16x16x32_bf16(af[i], bfv[j], acc[i][j], 0, 0, 0);
  };

  int nk = K >> 5;  // 24
  stageAB(0, 0);
  stageAB(1, 32);
  WAITP();
  RBAR;
  int cur = 0;
  for (int kt = 0; kt < nk; ++kt) {
    comp(cur);
    if (kt + 2 < nk) {
      RBAR;
      stageAB(cur, (kt + 2) * 32);
      WAITP();
      RBAR;
    } else if (kt + 1 < nk) {
      WAITV0;
      RBAR;
    }
    cur ^= 1;
  }

  #pragma unroll
  for (int i = 0; i < MI; ++i) {
    #pragma unroll
    for (int j = 0; j < 4; ++j) {
      #pragma unroll
      for (int r = 0; r < 4; ++r) {
        int row = m0 + wm + i * 16 + lg * 4 + r;
        int col = n0 + wn + j * 16 + ln;
        float v = acc[i][j][r];
        if (EPI == 0) {
          v += bias[col];
          ((unsigned short*)outp)[(size_t)bz * sO + (size_t)row * N + col] = f2bf(v);
        } else {
          v += bias[row] + resid[(size_t)bz * sR + (size_t)row * N + col];
          ((float*)outp)[(size_t)bz * sO + (size_t)row * N + col] = v;
        }
      }
    }
  }
}

// ------- attention: cross-tile pipeline — QK(t+1) overlaps softmax+PV(t) ---------
// 4 waves x QBLK=32, KVBLK=64, 32x32x16; lane q=lane&31 owns a softmax row; m=0.
// 3-buffer K/V LDS (48KB): tile t in buf t%3; stage(t+2) issued at iter t into the
// buffer vacated by tile t-1 (race-free: last read of t-1 was before this iter's
// barrier). One vmcnt(0)+barrier per iter covers stage(t+1) with ~1 tile of flight.
__global__ __launch_bounds__(256, 3) void k_attn(const unsigned short* __restrict__ qkvt,
                                                 const unsigned short* __restrict__ ekvt,
                                                 const unsigned short* __restrict__ vcat,
                                                 unsigned short* __restrict__ at) {
  int bid = blockIdx.x;
  int swb = (bid & 7) * 96 + (bid >> 3);  // XCD-contiguous head groups
  int t0 = (swb & 7) * 128, bh = swb >> 3, b = bh / 12, h = bh % 12;
  int tid = threadIdx.x, w = tid >> 6, lane = tid & 63;
  int ql = lane & 31, hi = lane >> 5;
  __shared__ unsigned short Ks[3][4096], Vs[3][4096];  // 48KB

  const float QSC = 0.125f * 1.44269504089f;
  bf16x8 aq[4];
  const unsigned short* qrow = qkvt + ((size_t)(b * 1024 + t0 + w * 32 + ql)) * 2304 + h * 192;
  #pragma unroll
  for (int jc = 0; jc < 4; ++jc) {
    ushort8v qv = *(const ushort8v*)(qrow + jc * 16 + hi * 8);
    bf16x8 o;
    #pragma unroll
    for (int e = 0; e < 8; ++e) o[e] = (short)f2bf(bf2f(qv[e]) * QSC);
    aq[jc] = o;
  }

  int rloc = w * 16 + (lane >> 3);
  int chunk = (lane & 7) ^ (lane >> 3);
  const unsigned short* ke_st = ekvt + ((size_t)(b * 256 + rloc)) * 1536 + h * 128 + chunk * 8;
  const unsigned short* kq_st = qkvt + ((long)b * 1024 - 256 + rloc) * 2304 + h * 192 + 64 + chunk * 8;
  const unsigned short* v_st  = vcat + ((size_t)(bh * 64 + rloc)) * 1280 + chunk * 8;

  auto stage = [&](int nb, int tn) {  // 4 gload16 into buf nb
    const unsigned short* ks;
    size_t rstep;
    if (tn < 4) { ks = ke_st + (size_t)tn * 64 * 1536; rstep = 8 * 1536; }
    else        { ks = kq_st + (size_t)tn * 64 * 2304; rstep = 8 * 2304; }
    unsigned short* kdd = &Ks[nb][0] + w * 1024;
    unsigned short* vdd = &Vs[nb][0] + w * 1024;
    const unsigned short* vs = v_st + tn * 64;
    gload16(ks, kdd);
    gload16(ks + rstep, kdd + 512);
    gload16(vs, vdd);
    gload16(vs + 8 * 1280, vdd + 512);
  };

  int xp = (ql & 7) << 4;
  auto qk = [&](int nb, f32x16& s0v, f32x16& s1v) {  // 8 MFMA: sf = P^T[s][q]
    const char* kbase = (const char*)&Ks[nb][0] + ql * 128;
    __builtin_amdgcn_s_setprio(1);
    #pragma unroll
    for (int jc = 0; jc < 4; ++jc) {
      int off = (jc * 32 + hi * 16) ^ xp;
      bf16x8 k0f = *(const bf16x8*)(kbase + off);
      bf16x8 k1f = *(const bf16x8*)(kbase + 4096 + off);
      s0v = __builtin_amdgcn_mfma_f32_32x32x16_bf16(k0f, aq[jc], s0v, 0, 0, 0);
      s1v = __builtin_amdgcn_mfma_f32_32x32x16_bf16(k1f, aq[jc], s1v, 0, 0, 0);
    }
    __builtin_amdgcn_s_setprio(0);
  };

  f32x16 acc0, acc1, sfP0, sfP1;
  #pragma unroll
  for (int r = 0; r < 16; ++r) { acc0[r] = 0.f; acc1[r] = 0.f; sfP0[r] = 0.f; sfP1[r] = 0.f; }
  float l = 0.f;

  // prologue: stage tiles 0,1; wait tile0 (counted: Q + stage0 forced, stage1 flies)
  stage(0, 0);
  stage(1, 1);
  WAITV4;
  __syncthreads();
  qk(0, sfP0, sfP1);  // sfP = scores(tile 0)

  for (int t = 0; t < 20; ++t) {
    if (t < 19) WAITV0;  // force stage(t+1) landed (only outstanding loads)
    __syncthreads();

    // QK(t+1) first: MFMA pipe busy while VALU does softmax(t) below
    f32x16 sN0, sN1;
    #pragma unroll
    for (int r = 0; r < 16; ++r) { sN0[r] = 0.f; sN1[r] = 0.f; }
    if (t < 19) qk((t + 1) % 3, sN0, sN1);

    if (t + 2 < 20) stage((t + 2) % 3, t + 2);  // into buf vacated by tile t-1

    // softmax(t): exp fused into pack; then PV(t)
    const char* vbase = (const char*)&Vs[t % 3][0] + ql * 128;
    #pragma unroll
    for (int sb = 0; sb < 2; ++sb) {
      unsigned pk[8];
      #pragma unroll
      for (int i = 0; i < 8; ++i) {
        float ea = exp2a(sb ? sfP1[2 * i] : sfP0[2 * i]);
        float eb = exp2a(sb ? sfP1[2 * i + 1] : sfP0[2 * i + 1]);
        l += ea + eb;
        pk[i] = cvtpk(ea, eb);
      }
      plswap(pk[0], pk[2]);
      plswap(pk[1], pk[3]);
      plswap(pk[4], pk[6]);
      plswap(pk[5], pk[7]);
      bf16x8 fj0 = mkfrag(pk[0], pk[1], pk[2], pk[3]);
      bf16x8 fj1 = mkfrag(pk[4], pk[5], pk[6], pk[7]);
      __builtin_amdgcn_s_setprio(1);
      #pragma unroll
      for (int jj = 0; jj < 2; ++jj) {
        int off = (sb * 64 + jj * 32 + hi * 16) ^ xp;
        bf16x8 v0f = *(const bf16x8*)(vbase + off);
        bf16x8 v1f = *(const bf16x8*)(vbase + 4096 + off);
        bf16x8 pf = jj ? fj1 : fj0;
        acc0 = __builtin_amdgcn_mfma_f32_32x32x16_bf16(v0f, pf, acc0, 0, 0, 0);
        acc1 = __builtin_amdgcn_mfma_f32_32x32x16_bf16(v1f, pf, acc1, 0, 0, 0);
      }
      __builtin_amdgcn_s_setprio(0);
    }

    sfP0 = sN0;
    sfP1 = sN1;
  }

  l += __shfl_xor(l, 32);
  float rl = 1.f / l;
  unsigned short* orow = at + ((size_t)(b * 1024 + t0 + w * 32 + ql)) * 768 + h * 64;
  #pragma unroll
  for (int cb = 0; cb < 2; ++cb) {
    #pragma unroll
    for (int g = 0; g < 4; ++g) {
      int c = cb * 32 + g * 8 + hi * 4;
      ushort4v o;
      #pragma unroll
      for (int i = 0; i < 4; ++i) {
        float v = (cb ? acc1[g * 4 + i] : acc0[g * 4 + i]) * rl;
        o[i] = f2bf(v);
      }
      *(ushort4v*)(orow + c) = o;
    }
  }
}

// ---------------- launch ----------------
extern "C" void kernel_launch(void* const* d_in, const int* in_sizes, int n_in,
                              void* d_out, int out_size, void* d_ws, size_t ws_size,
                              hipStream_t stream) {
  const float* x      = (const float*)d_in[0];
  const float* enc    = (const float*)d_in[1];
  const float* gn_w   = (const float*)d_in[2];
  const float* gn_b   = (const float*)d_in[3];
  const float* qkv_w  = (const float*)d_in[4];
  const float* qkv_b  = (const float*)d_in[5];
  const float* enc_w  = (const float*)d_in[6];
  const float* enc_b  = (const float*)d_in[7];
  const float* proj_w = (const float*)d_in[8];
  const float* proj_b = (const float*)d_in[9];
  float* out = (float*)d_out;

  char* ws = (char*)d_ws;
  unsigned short* w_qkv = (unsigned short*)(ws + 0);
  unsigned short* w_enc = (unsigned short*)(ws + 3538944);
  unsigned short* w_prj = (unsigned short*)(ws + 5898240);
  unsigned short* xn_t  = (unsigned short*)(ws + 7077888);
  unsigned short* enc_t = (unsigned short*)(ws + 19660800);
  unsigned short* qkv_t = (unsigned short*)(ws + 22806528);
  unsigned short* ekv_t = (unsigned short*)(ws + 60555264);
  unsigned short* vcat  = (unsigned short*)(ws + 66846720);
  unsigned short* a_t   = xn_t;

  k_cvt3<<<3456, 256, 0, stream>>>(qkv_w, enc_w, proj_w, w_qkv);
  k_gn<<<dim3(32, 8), 256, 0, stream>>>(x, gn_w, gn_b, xn_t);
  k_enc_tr<<<dim3(12, 4, 8), 256, 0, stream>>>(enc, enc_t);
  k_gemm<0, 128><<<dim3(64, 18, 1), 256, 0, stream>>>(xn_t, w_qkv, qkv_b, nullptr, qkv_t,
                                                      2304, 768, 0L, 0L, 0L, 0L);
  k_gemm<0, 64><<<dim3(32, 12, 1), 256, 0, stream>>>(enc_t, w_enc, enc_b, nullptr, ekv_t,
                                                     1536, 768, 0L, 0L, 0L, 0L);
  k_vcat<<<dim3(20, 96), 256, 0, stream>>>(qkv_t, ekv_t, vcat);
  k_attn<<<dim3(768), 256, 0, stream>>>(qkv_t, ekv_t, vcat, a_t);
  k_gemm<1, 64><<<dim3(12, 8, 8), 256, 0, stream>>>(w_prj, a_t, proj_b, x, out,
                                                    1024, 768, 0L, 786432L, 786432L, 786432L);
}

// Round 13
// 168.061 us; speedup vs baseline: 1.0558x; 1.0558x over previous
//
#include <hip/hip_runtime.h>

typedef __attribute__((ext_vector_type(8))) short bf16x8;
typedef __attribute__((ext_vector_type(4))) float f32x4;
typedef __attribute__((ext_vector_type(16))) float f32x16;
typedef __attribute__((ext_vector_type(4))) float float4v;
typedef __attribute__((ext_vector_type(4))) unsigned short ushort4v;
typedef __attribute__((ext_vector_type(8))) unsigned short ushort8v;

#define DEVINL __device__ __forceinline__

// B=8, C=768, T=1024, heads=12, ch=64, EC=768, S_enc=256, S_tot=1280, groups=32

DEVINL unsigned short f2bf(float f) {
  union { float f; unsigned u; } v; v.f = f;
  unsigned r = (v.u + 0x7fffu + ((v.u >> 16) & 1u)) >> 16;  // RNE
  return (unsigned short)r;
}
DEVINL float bf2f(unsigned short h) {
  union { unsigned u; float f; } v; v.u = ((unsigned)h) << 16;
  return v.f;
}
DEVINL float exp2a(float x) {
  float r; asm("v_exp_f32 %0, %1" : "=v"(r) : "v"(x)); return r;
}
DEVINL unsigned cvtpk(float lo, float hi) {  // dst = bf16(lo) | bf16(hi)<<16, RNE
  unsigned r;
  asm("v_cvt_pk_bf16_f32 %0, %1, %2" : "=v"(r) : "v"(lo), "v"(hi));
  return r;
}
DEVINL void gload16(const void* g, void* l) {
  __builtin_amdgcn_global_load_lds(
      (const __attribute__((address_space(1))) unsigned*)g,
      (__attribute__((address_space(3))) unsigned*)l, 16, 0, 0);
}
DEVINL void plswap(unsigned& a, unsigned& b) {  // a'={a.lo,b.lo}, b'={a.hi,b.hi}
  asm("v_permlane32_swap_b32 %0, %1" : "+v"(a), "+v"(b));
}
DEVINL bf16x8 mkfrag(unsigned a, unsigned b, unsigned c, unsigned d) {
  union { unsigned u[4]; bf16x8 v; } x;
  x.u[0] = a; x.u[1] = b; x.u[2] = c; x.u[3] = d;
  return x.v;
}
#define WAITV0 asm volatile("s_waitcnt vmcnt(0)" ::: "memory")
#define RBAR  __builtin_amdgcn_s_barrier()

// ---------------- fused fp32 -> bf16 weight convert (all 3 weights) ----------------
__global__ __launch_bounds__(256) void k_cvt3(const float* __restrict__ s0,
                                              const float* __restrict__ s1,
                                              const float* __restrict__ s2,
                                              unsigned short* __restrict__ d) {
  int i = blockIdx.x * 256 + threadIdx.x;  // 884736 float4s total
  const float* s; int off;
  if (i < 442368)      { s = s0; off = i; }
  else if (i < 737280) { s = s1; off = i - 442368; }
  else                 { s = s2; off = i - 737280; }
  float4v v = *(const float4v*)(s + (size_t)off * 4);
  ushort4v o;
  o[0] = f2bf(v[0]); o[1] = f2bf(v[1]); o[2] = f2bf(v[2]); o[3] = f2bf(v[3]);
  *(ushort4v*)(d + (size_t)i * 4) = o;
}

// ---------------- GroupNorm + transpose -> xn_t[b][t][c] bf16 ----------------
__global__ __launch_bounds__(256) void k_gn(const float* __restrict__ x,
                                            const float* __restrict__ gw,
                                            const float* __restrict__ gb,
                                            unsigned short* __restrict__ xnt) {
  int g = blockIdx.x, b = blockIdx.y, tid = threadIdx.x;
  const float* xb = x + ((size_t)b * 768 + g * 24) * 1024;
  float s = 0.f, ss = 0.f;
  for (int i = tid; i < 6144; i += 256) {
    float4v v = *(const float4v*)(xb + (size_t)i * 4);
    s += v[0] + v[1] + v[2] + v[3];
    ss += v[0] * v[0] + v[1] * v[1] + v[2] * v[2] + v[3] * v[3];
  }
  #pragma unroll
  for (int o = 32; o > 0; o >>= 1) { s += __shfl_down(s, o); ss += __shfl_down(ss, o); }
  __shared__ float rs[4], rss[4], stat[2];
  int w = tid >> 6;
  if ((tid & 63) == 0) { rs[w] = s; rss[w] = ss; }
  __syncthreads();
  if (tid == 0) {
    float S = rs[0] + rs[1] + rs[2] + rs[3], SS = rss[0] + rss[1] + rss[2] + rss[3];
    float mean = S / 24576.f;
    float var = SS / 24576.f - mean * mean;
    stat[0] = mean; stat[1] = rsqrtf(fmaxf(var, 0.f) + 1e-5f);
  }
  __syncthreads();
  float mean = stat[0], rstd = stat[1];
  float wv[24], bv[24];
  #pragma unroll
  for (int c = 0; c < 24; ++c) { wv[c] = gw[g * 24 + c]; bv[c] = gb[g * 24 + c]; }
  for (int it = 0; it < 4; ++it) {
    int t = it * 256 + tid;
    ushort8v ov[3];
    #pragma unroll
    for (int c = 0; c < 24; ++c) {
      float v = xb[(size_t)c * 1024 + t];
      ov[c >> 3][c & 7] = f2bf((v - mean) * rstd * wv[c] + bv[c]);
    }
    ushort8v* dst = (ushort8v*)(xnt + ((size_t)(b * 1024 + t)) * 768 + g * 24);
    dst[0] = ov[0]; dst[1] = ov[1]; dst[2] = ov[2];
  }
}

// ---------------- encoder transpose -> enc_t[b][s][c] bf16 ----------------
__global__ __launch_bounds__(256) void k_enc_tr(const float* __restrict__ enc,
                                                unsigned short* __restrict__ et) {
  int ct = blockIdx.x * 64, st = blockIdx.y * 64, b = blockIdx.z, tid = threadIdx.x;
  __shared__ unsigned short L[64 * 72];
  #pragma unroll
  for (int it = 0; it < 4; ++it) {
    int idx = it * 256 + tid; int r = idx >> 4, ch = idx & 15;
    float4v v = *(const float4v*)(enc + ((size_t)(b * 768 + ct + r)) * 256 + st + ch * 4);
    ushort4v o;
    o[0] = f2bf(v[0]); o[1] = f2bf(v[1]); o[2] = f2bf(v[2]); o[3] = f2bf(v[3]);
    *(ushort4v*)&L[r * 72 + ch * 4] = o;
  }
  __syncthreads();
  #pragma unroll
  for (int it = 0; it < 2; ++it) {
    int idx = it * 256 + tid; int s = idx >> 3, ch = idx & 7;
    ushort8v o;
    #pragma unroll
    for (int j = 0; j < 8; ++j) o[j] = L[(ch * 8 + j) * 72 + s];
    *(ushort8v*)(et + ((size_t)(b * 256 + st + s)) * 768 + ct + ch * 8) = o;
  }
}

// ---------------- build vcat[bh][c][s] bf16 ----------------
__global__ __launch_bounds__(256) void k_vcat(const unsigned short* __restrict__ qkvt,
                                              const unsigned short* __restrict__ ekvt,
                                              unsigned short* __restrict__ vcat) {
  int s0 = blockIdx.x * 64, bh = blockIdx.y, b = bh / 12, h = bh % 12, tid = threadIdx.x;
  __shared__ unsigned short L[64 * 72];
  #pragma unroll
  for (int it = 0; it < 2; ++it) {
    int idx = it * 256 + tid; int s = idx >> 3, ch = idx & 7;
    int sg = s0 + s;
    const unsigned short* src = (sg < 256)
        ? ekvt + ((size_t)(b * 256 + sg)) * 1536 + h * 128 + 64 + ch * 8
        : qkvt + ((size_t)(b * 1024 + sg - 256)) * 2304 + h * 192 + 128 + ch * 8;
    *(ushort8v*)&L[s * 72 + ch * 8] = *(const ushort8v*)src;
  }
  __syncthreads();
  #pragma unroll
  for (int it = 0; it < 2; ++it) {
    int idx = it * 256 + tid; int c = idx >> 3, ch = idx & 7;
    ushort8v o;
    #pragma unroll
    for (int j = 0; j < 8; ++j) o[j] = L[(ch * 8 + j) * 72 + c];
    *(ushort8v*)(vcat + ((size_t)bh * 64 + c) * 1280 + s0 + ch * 8) = o;
  }
}

// ------ GEMM: C[M][N] = A[M][K]*B[N][K]^T. 32x32x16 MFMA (half the LDS reads), ----
// BK=32, 3-buf counted pipeline (R8 form). Swizzle: slot ^= (row>>1)&3 (32-bank
// conflict-free for the 64B-row b128 pattern); staging pre-swizzles global chunk.
template <int EPI, int BM>
__global__ __launch_bounds__(256, 3) void k_gemm(const unsigned short* __restrict__ A,
                                                 const unsigned short* __restrict__ B,
                                                 const float* __restrict__ bias,
                                                 const float* __restrict__ resid,
                                                 void* __restrict__ outp,
                                                 int N, int K,
                                                 long sA, long sB, long sO, long sR) {
  constexpr int R32 = BM / 64;  // 32-row A-frags per wave: BM=128 -> 2, BM=64 -> 1
  int bz = blockIdx.z;
  int m0 = blockIdx.x * BM, n0 = blockIdx.y * 128;
  const unsigned short* Ab = A + (size_t)bz * sA + (size_t)m0 * K;
  const unsigned short* Bb = B + (size_t)bz * sB + (size_t)n0 * K;
  __shared__ unsigned short As[3][BM * 32], Bs[3][128 * 32];
  int tid = threadIdx.x, lane = tid & 63, w = tid >> 6;
  int l31 = lane & 31, hi2 = lane >> 5;
  int wm = (w >> 1) * (BM / 2), wn = (w & 1) * 64;
  // staging: row sr, slot sc; global chunk pre-swizzled with f(r) = (r>>1)&3
  int sr = tid >> 2, sc = tid & 3;
  int schunk = (sc ^ ((sr >> 1) & 3)) * 8;
  const unsigned short* gA = Ab + (size_t)sr * K + schunk;
  const unsigned short* gB = Bb + (size_t)sr * K + schunk;

  f32x16 acc[R32][2];
  #pragma unroll
  for (int i = 0; i < R32; ++i)
    #pragma unroll
    for (int j = 0; j < 2; ++j)
      #pragma unroll
      for (int r = 0; r < 16; ++r) acc[i][j][r] = 0.f;

  auto stageAB = [&](int buf, int k0) {  // BM=128: 4 issues; BM=64: 3
    unsigned short* ad = &As[buf][0] + w * 512;
    unsigned short* bd = &Bs[buf][0] + w * 512;
    gload16(gA + k0, ad);
    if constexpr (BM == 128) gload16(gA + (size_t)64 * K + k0, ad + 2048);
    gload16(gB + k0, bd);
    gload16(gB + (size_t)64 * K + k0, bd + 2048);
  };
  auto WAITP = [&] {
    if constexpr (BM == 128) asm volatile("s_waitcnt vmcnt(4)" ::: "memory");
    else                     asm volatile("s_waitcnt vmcnt(3)" ::: "memory");
  };
  auto comp = [&](int buf) {
    const char* abase = (const char*)&As[buf][0];
    const char* bbase = (const char*)&Bs[buf][0];
    #pragma unroll
    for (int kk = 0; kk < 2; ++kk) {
      bf16x8 afr[R32], bfr[2];
      #pragma unroll
      for (int ri = 0; ri < R32; ++ri) {
        int row = wm + ri * 32 + l31;
        int sl = (kk * 2 + hi2) ^ ((row >> 1) & 3);
        afr[ri] = *(const bf16x8*)(abase + row * 64 + sl * 16);
      }
      #pragma unroll
      for (int ci = 0; ci < 2; ++ci) {
        int row = wn + ci * 32 + l31;
        int sl = (kk * 2 + hi2) ^ ((row >> 1) & 3);
        bfr[ci] = *(const bf16x8*)(bbase + row * 64 + sl * 16);
      }
      #pragma unroll
      for (int ri = 0; ri < R32; ++ri)
        #pragma unroll
        for (int ci = 0; ci < 2; ++ci)
          acc[ri][ci] = __builtin_amdgcn_mfma_f32_32x32x16_bf16(afr[ri], bfr[ci],
                                                                acc[ri][ci], 0, 0, 0);
    }
  };

  int nk = K >> 5;  // 24
  stageAB(0, 0);
  stageAB(1, 32);
  WAITP();
  RBAR;
  int cur = 0;
  for (int kt = 0; kt < nk - 2; ++kt) {
    int pre = cur - 1; if (pre < 0) pre += 3;  // (cur+2)%3
    stageAB(pre, (kt + 2) * 32);
    comp(cur);
    WAITP();
    RBAR;
    ++cur; if (cur == 3) cur = 0;
  }
  comp(cur);
  WAITV0;
  RBAR;
  ++cur; if (cur == 3) cur = 0;
  comp(cur);

  #pragma unroll
  for (int ri = 0; ri < R32; ++ri) {
    #pragma unroll
    for (int ci = 0; ci < 2; ++ci) {
      #pragma unroll
      for (int rg = 0; rg < 16; ++rg) {
        int row = m0 + wm + ri * 32 + (rg & 3) + 8 * (rg >> 2) + 4 * hi2;
        int col = n0 + wn + ci * 32 + l31;
        float v = acc[ri][ci][rg];
        if (EPI == 0) {
          v += bias[col];
          ((unsigned short*)outp)[(size_t)bz * sO + (size_t)row * N + col] = f2bf(v);
        } else {
          v += bias[row] + resid[(size_t)bz * sR + (size_t)row * N + col];
          ((float*)outp)[(size_t)bz * sO + (size_t)row * N + col] = v;
        }
      }
    }
  }
}

// ---------------- attention (R9 proven form): swapped QK, in-reg softmax, m=0 -----
__global__ __launch_bounds__(256, 3) void k_attn(const unsigned short* __restrict__ qkvt,
                                                 const unsigned short* __restrict__ ekvt,
                                                 const unsigned short* __restrict__ vcat,
                                                 unsigned short* __restrict__ at) {
  int bid = blockIdx.x;
  int swb = (bid & 7) * 96 + (bid >> 3);  // XCD-contiguous head groups
  int t0 = (swb & 7) * 128, bh = swb >> 3, b = bh / 12, h = bh % 12;
  int tid = threadIdx.x, w = tid >> 6, lane = tid & 63;
  int ql = lane & 31, hi = lane >> 5;
  __shared__ unsigned short Ks[2][4096], Vs[2][4096];

  const float QSC = 0.125f * 1.44269504089f;
  bf16x8 aq[4];
  const unsigned short* qrow = qkvt + ((size_t)(b * 1024 + t0 + w * 32 + ql)) * 2304 + h * 192;
  #pragma unroll
  for (int jc = 0; jc < 4; ++jc) {
    ushort8v qv = *(const ushort8v*)(qrow + jc * 16 + hi * 8);
    bf16x8 o;
    #pragma unroll
    for (int e = 0; e < 8; ++e) o[e] = (short)f2bf(bf2f(qv[e]) * QSC);
    aq[jc] = o;
  }

  int rloc = w * 16 + (lane >> 3);
  int chunk = (lane & 7) ^ (lane >> 3);
  const unsigned short* ke_st = ekvt + ((size_t)(b * 256 + rloc)) * 1536 + h * 128 + chunk * 8;
  const unsigned short* kq_st = qkvt + ((long)b * 1024 - 256 + rloc) * 2304 + h * 192 + 64 + chunk * 8;
  const unsigned short* v_st  = vcat + ((size_t)(bh * 64 + rloc)) * 1280 + chunk * 8;
  unsigned short* kd = &Ks[0][0] + w * 1024;
  unsigned short* vd = &Vs[0][0] + w * 1024;

  auto stage = [&](int nb, int tn) {
    const unsigned short* ks;
    size_t rstep;
    if (tn < 4) { ks = ke_st + (size_t)tn * 64 * 1536; rstep = 8 * 1536; }
    else        { ks = kq_st + (size_t)tn * 64 * 2304; rstep = 8 * 2304; }
    unsigned short* kdd = kd + nb * 4096;
    unsigned short* vdd = vd + nb * 4096;
    const unsigned short* vs = v_st + tn * 64;
    gload16(ks, kdd);
    gload16(ks + rstep, kdd + 512);
    gload16(vs, vdd);
    gload16(vs + 8 * 1280, vdd + 512);
  };

  stage(0, 0);
  WAITV0;
  __syncthreads();

  f32x16 acc0, acc1;
  #pragma unroll
  for (int r = 0; r < 16; ++r) { acc0[r] = 0.f; acc1[r] = 0.f; }
  float l = 0.f;
  int xp = (ql & 7) << 4;

  for (int t = 0; t < 20; ++t) {
    int cur = t & 1;
    if (t < 19) stage(cur ^ 1, t + 1);

    // QK^T (swapped): sf = P^T[s][q]
    f32x16 sf0, sf1;
    #pragma unroll
    for (int r = 0; r < 16; ++r) { sf0[r] = 0.f; sf1[r] = 0.f; }
    const char* kbase = (const char*)&Ks[cur][0] + ql * 128;
    __builtin_amdgcn_s_setprio(1);
    #pragma unroll
    for (int jc = 0; jc < 4; ++jc) {
      int off = (jc * 32 + hi * 16) ^ xp;
      bf16x8 k0f = *(const bf16x8*)(kbase + off);
      bf16x8 k1f = *(const bf16x8*)(kbase + 4096 + off);
      sf0 = __builtin_amdgcn_mfma_f32_32x32x16_bf16(k0f, aq[jc], sf0, 0, 0, 0);
      sf1 = __builtin_amdgcn_mfma_f32_32x32x16_bf16(k1f, aq[jc], sf1, 0, 0, 0);
    }
    __builtin_amdgcn_s_setprio(0);

    // exp (scores O(1): m=0 exact; bf16 headroom ample)
    float pe[32];
    #pragma unroll
    for (int i = 0; i < 16; ++i) pe[i] = exp2a(sf0[i]);
    #pragma unroll
    for (int i = 0; i < 16; ++i) pe[16 + i] = exp2a(sf1[i]);

    const char* vbase = (const char*)&Vs[cur][0] + ql * 128;
    #pragma unroll
    for (int sb = 0; sb < 2; ++sb) {
      unsigned pk[8];
      #pragma unroll
      for (int i = 0; i < 8; ++i)
        pk[i] = cvtpk(pe[sb * 16 + 2 * i], pe[sb * 16 + 2 * i + 1]);
      plswap(pk[0], pk[2]);
      plswap(pk[1], pk[3]);
      plswap(pk[4], pk[6]);
      plswap(pk[5], pk[7]);
      bf16x8 fj0 = mkfrag(pk[0], pk[1], pk[2], pk[3]);
      bf16x8 fj1 = mkfrag(pk[4], pk[5], pk[6], pk[7]);
      __builtin_amdgcn_s_setprio(1);
      #pragma unroll
      for (int jj = 0; jj < 2; ++jj) {
        int off = (sb * 64 + jj * 32 + hi * 16) ^ xp;
        bf16x8 v0f = *(const bf16x8*)(vbase + off);
        bf16x8 v1f = *(const bf16x8*)(vbase + 4096 + off);
        bf16x8 pf = jj ? fj1 : fj0;
        acc0 = __builtin_amdgcn_mfma_f32_32x32x16_bf16(v0f, pf, acc0, 0, 0, 0);
        acc1 = __builtin_amdgcn_mfma_f32_32x32x16_bf16(v1f, pf, acc1, 0, 0, 0);
      }
      __builtin_amdgcn_s_setprio(0);
    }

    float s0 = 0.f, s1 = 0.f, s2 = 0.f, s3 = 0.f;
    #pragma unroll
    for (int i = 0; i < 8; ++i) {
      s0 += pe[i]; s1 += pe[8 + i]; s2 += pe[16 + i]; s3 += pe[24 + i];
    }
    l += (s0 + s1) + (s2 + s3);

    if (t < 19) WAITV0;
    __syncthreads();
  }

  l += __shfl_xor(l, 32);
  float rl = 1.f / l;
  unsigned short* orow = at + ((size_t)(b * 1024 + t0 + w * 32 + ql)) * 768 + h * 64;
  #pragma unroll
  for (int cb = 0; cb < 2; ++cb) {
    #pragma unroll
    for (int g = 0; g < 4; ++g) {
      int c = cb * 32 + g * 8 + hi * 4;
      ushort4v o;
      #pragma unroll
      for (int i = 0; i < 4; ++i) {
        float v = (cb ? acc1[g * 4 + i] : acc0[g * 4 + i]) * rl;
        o[i] = f2bf(v);
      }
      *(ushort4v*)(orow + c) = o;
    }
  }
}

// ---------------- launch ----------------
extern "C" void kernel_launch(void* const* d_in, const int* in_sizes, int n_in,
                              void* d_out, int out_size, void* d_ws, size_t ws_size,
                              hipStream_t stream) {
  const float* x      = (const float*)d_in[0];
  const float* enc    = (const float*)d_in[1];
  const float* gn_w   = (const float*)d_in[2];
  const float* gn_b   = (const float*)d_in[3];
  const float* qkv_w  = (const float*)d_in[4];
  const float* qkv_b  = (const float*)d_in[5];
  const float* enc_w  = (const float*)d_in[6];
  const float* enc_b  = (const float*)d_in[7];
  const float* proj_w = (const float*)d_in[8];
  const float* proj_b = (const float*)d_in[9];
  float* out = (float*)d_out;

  char* ws = (char*)d_ws;
  unsigned short* w_qkv = (unsigned short*)(ws + 0);
  unsigned short* w_enc = (unsigned short*)(ws + 3538944);
  unsigned short* w_prj = (unsigned short*)(ws + 5898240);
  unsigned short* xn_t  = (unsigned short*)(ws + 7077888);
  unsigned short* enc_t = (unsigned short*)(ws + 19660800);
  unsigned short* qkv_t = (unsigned short*)(ws + 22806528);
  unsigned short* ekv_t = (unsigned short*)(ws + 60555264);
  unsigned short* vcat  = (unsigned short*)(ws + 66846720);
  unsigned short* a_t   = xn_t;

  k_cvt3<<<3456, 256, 0, stream>>>(qkv_w, enc_w, proj_w, w_qkv);
  k_gn<<<dim3(32, 8), 256, 0, stream>>>(x, gn_w, gn_b, xn_t);
  k_enc_tr<<<dim3(12, 4, 8), 256, 0, stream>>>(enc, enc_t);
  // GEMM1 fused over batch: 8192 x 2304 x 768, BM=128
  k_gemm<0, 128><<<dim3(64, 18, 1), 256, 0, stream>>>(xn_t, w_qkv, qkv_b, nullptr, qkv_t,
                                                      2304, 768, 0L, 0L, 0L, 0L);
  // GEMM2 fused: 2048 x 1536 x 768, BM=64 (384 blocks)
  k_gemm<0, 64><<<dim3(32, 12, 1), 256, 0, stream>>>(enc_t, w_enc, enc_b, nullptr, ekv_t,
                                                     1536, 768, 0L, 0L, 0L, 0L);
  k_vcat<<<dim3(20, 96), 256, 0, stream>>>(qkv_t, ekv_t, vcat);
  k_attn<<<dim3(768), 256, 0, stream>>>(qkv_t, ekv_t, vcat, a_t);
  // GEMM3: out[b][o][t] = proj(a) + bias + x ; BM=64 (768 blocks)
  k_gemm<1, 64><<<dim3(12, 8, 8), 256, 0, stream>>>(w_prj, a_t, proj_b, x, out,
                                                    1024, 768, 0L, 786432L, 786432L, 786432L);
}